// Round 1
// baseline (9446.152 us; speedup 1.0000x reference)
//
#include <hip/hip_runtime.h>
#include <hip/hip_bf16.h>

// C_VAE_NET: 2-layer LSTM encoder -> reparam -> 2-layer LSTM decoder -> dense.
// B=512, T=128, D=128, Z=64, U(enc)=U(dec)=512, gates 4U=2048.
// Strategy: bf16 MFMA (16x16x32) everywhere, fp32 accumulate & cell state.
// Recurrent step folds input projection via concatenated K: [h_{t-1}; x_t] @ [WhT | WxT].
// Weight columns pre-permuted so gates (i,f,c,o) of unit u are columns 4u..4u+3,
// letting the gate nonlinearity run in-register via 3 shfl_xor.

#define B_  512
#define T_  128
#define D_  128
#define Z_  64
#define U_  512
#define G4_ 2048

typedef __attribute__((ext_vector_type(8))) short short8; // 8 x bf16
typedef __attribute__((ext_vector_type(4))) float f32x4;

__device__ __forceinline__ float sigm(float x)  { return 1.0f / (1.0f + __expf(-x)); }
__device__ __forceinline__ float tanhf_(float x){ return 2.0f / (1.0f + __expf(-2.0f * x)) - 1.0f; }

// ---------------------------------------------------------------------------
// prep kernels
// ---------------------------------------------------------------------------

__global__ void convert_bf16(const float* __restrict__ src, __hip_bfloat16* __restrict__ dst, int n) {
    int i = blockIdx.x * 256 + threadIdx.x;
    if (i < n) dst[i] = __float2bfloat16(src[i]);
}

// dst[n][koff+k] = bf16(src[k][pcol(n)]) ; src is [K][Nsrc] row-major fp32.
// perm: pcol = (n&3)*512 + (n>>2)  (gate-interleave for LSTM weights), else n.
__global__ void conv_weight(const float* __restrict__ src, __hip_bfloat16* __restrict__ dst,
                            int K, int Nrows, int Nsrc, int ldd, int koff, int perm) {
    int idx = blockIdx.x * 256 + threadIdx.x;
    if (idx >= K * Nrows) return;
    int n = idx / K, k = idx - n * K;
    int pc = perm ? ((n & 3) * 512 + (n >> 2)) : n;
    dst[(size_t)n * ldd + koff + k] = __float2bfloat16(src[(size_t)k * Nsrc + pc]);
}

__global__ void conv_bias(const float* __restrict__ src, float* __restrict__ dst) {
    int n = blockIdx.x * 256 + threadIdx.x;
    if (n < G4_) dst[n] = src[(n & 3) * 512 + (n >> 2)];
}

// ---------------------------------------------------------------------------
// LSTM recurrent step: g = bias + h_{t-1} @ Wh + x_t @ Wx ; gates ; c,h update
// hs: [B,T,U] bf16 (reads row t-1, writes row t). xin: [B,T,DIN] bf16.
// WT: [2048][512+DIN] bf16 (row n = permuted gate column; cols: Wh then Wx).
// 256 blocks x 256 thr (4 waves); block tile 64(M)x64(N); wave tile 32x32.
// ---------------------------------------------------------------------------
template <int DIN>
__global__ __launch_bounds__(256) void lstm_step(
    __hip_bfloat16* __restrict__ hs,
    const __hip_bfloat16* __restrict__ xin,
    const __hip_bfloat16* __restrict__ WT,
    const float* __restrict__ bias,
    float* __restrict__ c_state,
    int t) {
    constexpr int LDW = U_ + DIN;
    const int bid = blockIdx.x;
    const int xcd = bid & 7, slot = bid >> 3;             // keep a fixed N-slice per XCD -> W L2-hot
    const int n0 = xcd * 256 + (slot & 3) * 64;
    const int m0 = (slot >> 2) * 64;
    const int tid = threadIdx.x;
    const int w = tid >> 6, l = tid & 63, lr = l & 15, lq = l >> 4;
    const int wm = (w >> 1) * 32, wn = (w & 1) * 32;

    f32x4 acc[2][2];
#pragma unroll
    for (int j = 0; j < 2; j++) {
        float bv = bias[n0 + wn + j * 16 + lr];
#pragma unroll
        for (int i = 0; i < 2; i++)
#pragma unroll
            for (int r = 0; r < 4; r++) acc[i][j][r] = bv;
    }

    const int rowA0 = m0 + wm + lr;
    const int rowA1 = m0 + wm + 16 + lr;

    if (t > 0) {
#pragma unroll 4
        for (int k0 = 0; k0 < U_; k0 += 32) {
            short8 a0 = *(const short8*)(hs + ((size_t)rowA0 * T_ + (t - 1)) * U_ + k0 + lq * 8);
            short8 a1 = *(const short8*)(hs + ((size_t)rowA1 * T_ + (t - 1)) * U_ + k0 + lq * 8);
            short8 b0 = *(const short8*)(WT + (size_t)(n0 + wn + lr) * LDW + k0 + lq * 8);
            short8 b1 = *(const short8*)(WT + (size_t)(n0 + wn + 16 + lr) * LDW + k0 + lq * 8);
            acc[0][0] = __builtin_amdgcn_mfma_f32_16x16x32_bf16(a0, b0, acc[0][0], 0, 0, 0);
            acc[0][1] = __builtin_amdgcn_mfma_f32_16x16x32_bf16(a0, b1, acc[0][1], 0, 0, 0);
            acc[1][0] = __builtin_amdgcn_mfma_f32_16x16x32_bf16(a1, b0, acc[1][0], 0, 0, 0);
            acc[1][1] = __builtin_amdgcn_mfma_f32_16x16x32_bf16(a1, b1, acc[1][1], 0, 0, 0);
        }
    }
#pragma unroll
    for (int k0 = 0; k0 < DIN; k0 += 32) {
        short8 a0 = *(const short8*)(xin + ((size_t)rowA0 * T_ + t) * DIN + k0 + lq * 8);
        short8 a1 = *(const short8*)(xin + ((size_t)rowA1 * T_ + t) * DIN + k0 + lq * 8);
        short8 b0 = *(const short8*)(WT + (size_t)(n0 + wn + lr) * LDW + U_ + k0 + lq * 8);
        short8 b1 = *(const short8*)(WT + (size_t)(n0 + wn + 16 + lr) * LDW + U_ + k0 + lq * 8);
        acc[0][0] = __builtin_amdgcn_mfma_f32_16x16x32_bf16(a0, b0, acc[0][0], 0, 0, 0);
        acc[0][1] = __builtin_amdgcn_mfma_f32_16x16x32_bf16(a0, b1, acc[0][1], 0, 0, 0);
        acc[1][0] = __builtin_amdgcn_mfma_f32_16x16x32_bf16(a1, b0, acc[1][0], 0, 0, 0);
        acc[1][1] = __builtin_amdgcn_mfma_f32_16x16x32_bf16(a1, b1, acc[1][1], 0, 0, 0);
    }

    // gate epilogue: C frag col = lane&15 (gate = lane&3), row = (lane>>4)*4 + r.
    const int g = l & 3;
#pragma unroll
    for (int i = 0; i < 2; i++)
#pragma unroll
        for (int j = 0; j < 2; j++)
#pragma unroll
            for (int r = 0; r < 4; r++) {
                float v = acc[i][j][r];
                float a1 = __shfl_xor(v, 1); // gate g^1
                float a2 = __shfl_xor(v, 2); // gate g^2
                float a3 = __shfl_xor(v, 3); // gate g^3
                if (g == 0) {                // lane holds gate i; a1=f, a2=c, a3=o
                    int col = n0 + wn + j * 16 + lr;
                    int u = col >> 2;
                    int row = m0 + wm + i * 16 + lq * 4 + r;
                    float ig = sigm(v), fg = sigm(a1), cg = tanhf_(a2), og = sigm(a3);
                    float cp = (t == 0) ? 0.0f : c_state[(size_t)row * U_ + u];
                    float cn = fg * cp + ig * cg;
                    c_state[(size_t)row * U_ + u] = cn;
                    hs[((size_t)row * T_ + t) * U_ + u] = __float2bfloat16(og * tanhf_(cn));
                }
            }
}

// ---------------------------------------------------------------------------
// dense: out[M,N] = A[M,K](bf16) @ WT[N,K](bf16) + bias ; fp32 out, row-major.
// block 128(M)x64(N), 4 waves stacked on M, wave 32x64.
// ---------------------------------------------------------------------------
__global__ __launch_bounds__(256) void gemm_bias(
    const __hip_bfloat16* __restrict__ A, const __hip_bfloat16* __restrict__ WT,
    const float* __restrict__ bias, float* __restrict__ out, int K, int N) {
    const int m0 = blockIdx.x * 128, n0 = blockIdx.y * 64;
    const int tid = threadIdx.x, w = tid >> 6, l = tid & 63, lr = l & 15, lq = l >> 4;
    const int wm = w * 32;

    f32x4 acc[2][4];
#pragma unroll
    for (int j = 0; j < 4; j++) {
        float bv = bias[n0 + j * 16 + lr];
#pragma unroll
        for (int i = 0; i < 2; i++)
#pragma unroll
            for (int r = 0; r < 4; r++) acc[i][j][r] = bv;
    }
    for (int k0 = 0; k0 < K; k0 += 32) {
        short8 a[2], b[4];
#pragma unroll
        for (int i = 0; i < 2; i++)
            a[i] = *(const short8*)(A + (size_t)(m0 + wm + i * 16 + lr) * K + k0 + lq * 8);
#pragma unroll
        for (int j = 0; j < 4; j++)
            b[j] = *(const short8*)(WT + (size_t)(n0 + j * 16 + lr) * K + k0 + lq * 8);
#pragma unroll
        for (int i = 0; i < 2; i++)
#pragma unroll
            for (int j = 0; j < 4; j++)
                acc[i][j] = __builtin_amdgcn_mfma_f32_16x16x32_bf16(a[i], b[j], acc[i][j], 0, 0, 0);
    }
#pragma unroll
    for (int i = 0; i < 2; i++)
#pragma unroll
        for (int j = 0; j < 4; j++)
#pragma unroll
            for (int r = 0; r < 4; r++)
                out[(size_t)(m0 + wm + i * 16 + lq * 4 + r) * N + n0 + j * 16 + lr] = acc[i][j][r];
}

// ---------------------------------------------------------------------------
// reparameterize: z = zm + exp(0.5*zlv)*eps ; also emits exp(zlv) and z in bf16
// ---------------------------------------------------------------------------
__global__ void reparam(const float* __restrict__ zm, const float* __restrict__ zlv,
                        const float* __restrict__ eps, float* __restrict__ z,
                        float* __restrict__ ezlv, __hip_bfloat16* __restrict__ zb, int n) {
    int i = blockIdx.x * 256 + threadIdx.x;
    if (i >= n) return;
    float m = zm[i], lv = zlv[i];
    float zi = m + expf(0.5f * lv) * eps[i];
    z[i] = zi;
    ezlv[i] = expf(lv);
    zb[i] = __float2bfloat16(zi);
}

// ---------------------------------------------------------------------------

extern "C" void kernel_launch(void* const* d_in, const int* in_sizes, int n_in,
                              void* d_out, int out_size, void* d_ws, size_t ws_size,
                              hipStream_t stream) {
    const float* x    = (const float*)d_in[0];
    const float* eps  = (const float*)d_in[1];
    const float* e0Wx = (const float*)d_in[2];
    const float* e0Wh = (const float*)d_in[3];
    const float* e0b  = (const float*)d_in[4];
    const float* e1Wx = (const float*)d_in[5];
    const float* e1Wh = (const float*)d_in[6];
    const float* e1b  = (const float*)d_in[7];
    const float* d0Wx = (const float*)d_in[8];
    const float* d0Wh = (const float*)d_in[9];
    const float* d0b  = (const float*)d_in[10];
    const float* d1Wx = (const float*)d_in[11];
    const float* d1Wh = (const float*)d_in[12];
    const float* d1b  = (const float*)d_in[13];
    const float* Wm   = (const float*)d_in[14];
    const float* bm   = (const float*)d_in[15];
    const float* Wv   = (const float*)d_in[16];
    const float* bv   = (const float*)d_in[17];
    const float* Wo   = (const float*)d_in[18];
    const float* bo   = (const float*)d_in[19];
    float* out = (float*)d_out;

    char* ws = (char*)d_ws;
    size_t off = 0;
    auto alloc = [&](size_t bytes) -> char* {
        off = (off + 255) & ~(size_t)255;
        char* p = ws + off;
        off += bytes;
        return p;
    };
    __hip_bfloat16* hsA  = (__hip_bfloat16*)alloc((size_t)B_ * T_ * U_ * 2); // 64MB
    __hip_bfloat16* hsB  = (__hip_bfloat16*)alloc((size_t)B_ * T_ * U_ * 2); // 64MB
    __hip_bfloat16* xb   = (__hip_bfloat16*)alloc((size_t)B_ * T_ * D_ * 2); // 16MB
    __hip_bfloat16* zb   = (__hip_bfloat16*)alloc((size_t)B_ * T_ * Z_ * 2); //  8MB
    __hip_bfloat16* WTe0 = (__hip_bfloat16*)alloc((size_t)G4_ * (U_ + D_) * 2);
    __hip_bfloat16* WTe1 = (__hip_bfloat16*)alloc((size_t)G4_ * (U_ + U_) * 2);
    __hip_bfloat16* WTd0 = (__hip_bfloat16*)alloc((size_t)G4_ * (U_ + Z_) * 2);
    __hip_bfloat16* WTd1 = (__hip_bfloat16*)alloc((size_t)G4_ * (U_ + U_) * 2);
    __hip_bfloat16* WmT  = (__hip_bfloat16*)alloc((size_t)Z_ * U_ * 2);
    __hip_bfloat16* WvT  = (__hip_bfloat16*)alloc((size_t)Z_ * U_ * 2);
    __hip_bfloat16* WoT  = (__hip_bfloat16*)alloc((size_t)D_ * U_ * 2);
    float* be0 = (float*)alloc(G4_ * 4);
    float* be1 = (float*)alloc(G4_ * 4);
    float* bd0 = (float*)alloc(G4_ * 4);
    float* bd1 = (float*)alloc(G4_ * 4);
    float* cst = (float*)alloc((size_t)B_ * U_ * 4);

    // ---- prep: bf16 conversions + weight transpose/permutes ----
    convert_bf16<<<(B_ * T_ * D_ + 255) / 256, 256, 0, stream>>>(x, xb, B_ * T_ * D_);

    auto cw = [&](const float* src, __hip_bfloat16* dst, int K, int Nrows, int Nsrc, int ldd, int koff, int perm) {
        conv_weight<<<(K * Nrows + 255) / 256, 256, 0, stream>>>(src, dst, K, Nrows, Nsrc, ldd, koff, perm);
    };
    cw(e0Wh, WTe0, U_, G4_, G4_, U_ + D_, 0, 1);
    cw(e0Wx, WTe0, D_, G4_, G4_, U_ + D_, U_, 1);
    cw(e1Wh, WTe1, U_, G4_, G4_, U_ + U_, 0, 1);
    cw(e1Wx, WTe1, U_, G4_, G4_, U_ + U_, U_, 1);
    cw(d0Wh, WTd0, U_, G4_, G4_, U_ + Z_, 0, 1);
    cw(d0Wx, WTd0, Z_, G4_, G4_, U_ + Z_, U_, 1);
    cw(d1Wh, WTd1, U_, G4_, G4_, U_ + U_, 0, 1);
    cw(d1Wx, WTd1, U_, G4_, G4_, U_ + U_, U_, 1);
    cw(Wm, WmT, U_, Z_, Z_, U_, 0, 0);
    cw(Wv, WvT, U_, Z_, Z_, U_, 0, 0);
    cw(Wo, WoT, U_, D_, D_, U_, 0, 0);
    conv_bias<<<G4_ / 256, 256, 0, stream>>>(e0b, be0);
    conv_bias<<<G4_ / 256, 256, 0, stream>>>(e1b, be1);
    conv_bias<<<G4_ / 256, 256, 0, stream>>>(d0b, bd0);
    conv_bias<<<G4_ / 256, 256, 0, stream>>>(d1b, bd1);

    // ---- encoder ----
    for (int t = 0; t < T_; ++t)
        lstm_step<D_><<<256, 256, 0, stream>>>(hsA, xb, WTe0, be0, cst, t);
    for (int t = 0; t < T_; ++t)
        lstm_step<U_><<<256, 256, 0, stream>>>(hsB, hsA, WTe1, be1, cst, t);

    // ---- latent heads + reparameterize ----
    const size_t oRecon = 0;
    const size_t oE   = (size_t)B_ * T_ * D_;             //  8388608
    const size_t oZm  = oE + (size_t)B_ * T_ * Z_;        // 12582912
    const size_t oZlv = oZm + (size_t)B_ * T_ * Z_;       // 16777216
    const size_t oZ   = oZlv + (size_t)B_ * T_ * Z_;      // 20971520

    gemm_bias<<<dim3(B_ * T_ / 128, Z_ / 64), 256, 0, stream>>>(hsB, WmT, bm, out + oZm, U_, Z_);
    gemm_bias<<<dim3(B_ * T_ / 128, Z_ / 64), 256, 0, stream>>>(hsB, WvT, bv, out + oZlv, U_, Z_);
    reparam<<<(B_ * T_ * Z_ + 255) / 256, 256, 0, stream>>>(out + oZm, out + oZlv, eps,
                                                            out + oZ, out + oE, zb, B_ * T_ * Z_);

    // ---- decoder ----
    for (int t = 0; t < T_; ++t)
        lstm_step<Z_><<<256, 256, 0, stream>>>(hsA, zb, WTd0, bd0, cst, t);
    for (int t = 0; t < T_; ++t)
        lstm_step<U_><<<256, 256, 0, stream>>>(hsB, hsA, WTd1, bd1, cst, t);

    // ---- output dense ----
    gemm_bias<<<dim3(B_ * T_ / 128, D_ / 64), 256, 0, stream>>>(hsB, WoT, bo, out + oRecon, U_, D_);
}